// Round 4
// baseline (165.587 us; speedup 1.0000x reference)
//
#include <hip/hip_runtime.h>

// RBF-MMD discriminator: B=512 rows, T=128 slabs, C=16, fp32.
// out = E_xx - 2*E_xy over per-slab RBF grams (slab weight 1 for t in {0,127},
// else 2; 254 weighted slab instances).
//
// R12: single-kernel fusion. Evidence R8-R11: all mmd-internal structural
// changes (tile-math halving, barrier removal, gather de-divergence) move
// total by <=1.5us -> mmd is small (~6-10us) and the timed region is
// dominated by the harness 256MiB poison fill (~41.5us @82% HBM) + fixed
// dispatch overhead. Only controllable term left: dispatch count. The
// finalize kernel (launch gap + 1-block kernel ~4-6us) is fused into
// mmd_kernel via the last-block ticket pattern: per-block release fence +
// device-scope atomicAdd on a ws counter (zeroed in-stream by a 4B
// hipMemsetAsync, since ws is re-poisoned every iteration); the block that
// draws ticket 3327 acquires and runs the exact finalize reduction (same
// summation order -> same rounding as the separate kernel).
// mmd internals = R10 (best measured): per-row staging, per-wave partial
// stores, no cross-wave block reduce.
// Per-entry math (R8): pure-bf16 dot (SCALE=sqrt(log2e) in operands),
// -|col|^2/2 log2-domain folded into MFMA K-slots 16/17 vs A={1,1},
// row-scale 2^-g_row epilogue. Kxx strip-pairs q>=a, q>a weighted 2x.

#define LOG2E 1.4426950408889634f
#define SCALE 1.2011224087864498f   // sqrt(LOG2E)

typedef __attribute__((ext_vector_type(8))) __bf16 bf16x8;
typedef __attribute__((ext_vector_type(4))) float floatx4;

union FragU { uint4 q; unsigned int u[4]; bf16x8 v; };

// 16B-aligned group-padded LDS row offset (dwords): 8 dw/row + 4 dw pad per 4 rows.
static __device__ __forceinline__ int off(int n) { return (n << 3) + ((n >> 2) << 2); }

static __device__ __forceinline__ unsigned short bfbits(__bf16 h) {
    union { __bf16 h; unsigned short s; } u; u.h = h; return u.s;
}
static __device__ __forceinline__ unsigned int packhh(__bf16 a, __bf16 b) {
    return (unsigned int)bfbits(a) | ((unsigned int)bfbits(b) << 16);
}

#define NSLOT 26
#define NBLK  (NSLOT * 128)          // 3328 blocks
#define ONEONE 0x3F803F80u           // packed bf16 {1.0, 1.0}

// grid (26,128): blockIdx.x = pair slot, blockIdx.y = t.
// slot<16: xy block, a=slot>>2 (A strip of X), q=slot&3 (col strip of Y).
// slot>=16: xx block over triangular (a,q), q>=a, weight 2 if q>a.
// 4 waves; wave w owns A rows a*128 + w*32 (two 16-row tiles).
__global__ __launch_bounds__(256, 8) void mmd_kernel(const float* __restrict__ x,
                                                     const float* __restrict__ y,
                                                     float* __restrict__ part,
                                                     unsigned int* __restrict__ cnt,
                                                     float* __restrict__ out) {
    __shared__ unsigned int AH[1152], BH[1152];
    __shared__ unsigned int BG[512];      // per B-row: {pack(-ghi,-glo),0,0,0}
    __shared__ float srg[128];            // g per A-row
    __shared__ unsigned int zero4[4];
    __shared__ int lastflag;
    __shared__ double dred[8];

    const int slot = blockIdx.x;
    const int t    = blockIdx.y;
    const int tid  = threadIdx.x;
    const int w    = tid >> 6;
    const int lane = tid & 63;
    const int quad = lane >> 4;
    const int l15  = lane & 15;
    const int qh   = quad & 1;

    int sa, sq, isxx;
    if (slot < 16) { isxx = 0; sa = slot >> 2; sq = slot & 3; }
    else {
        isxx = 1;
        const int s = slot - 16;
        if      (s < 4) { sa = 0; sq = s; }
        else if (s < 7) { sa = 1; sq = s - 3; }
        else if (s < 9) { sa = 2; sq = s - 5; }
        else            { sa = 3; sq = 3; }
    }

    if (tid == 0) { zero4[0] = 0u; zero4[1] = 0u; zero4[2] = 0u; zero4[3] = 0u; }

    // ---- staging: threads 0..127 convert A-rows (X), 128..255 B-rows ----
    {
        const int half = tid >> 7;
        const int r    = tid & 127;
        const int grow = (half ? sq : sa) * 128 + r;
        const float4* __restrict__ src4 =
            (half && !isxx) ? (const float4*)y : (const float4*)x;
        const size_t gb = (size_t)grow * 512 + t * 4;
        float4 f0 = src4[gb], f1 = src4[gb + 1], f2 = src4[gb + 2], f3 = src4[gb + 3];
        const float fs[16] = { f0.x, f0.y, f0.z, f0.w, f1.x, f1.y, f1.z, f1.w,
                               f2.x, f2.y, f2.z, f2.w, f3.x, f3.y, f3.z, f3.w };
        float g = 0.f;
        unsigned int hw[8];
#pragma unroll
        for (int p = 0; p < 8; ++p) {
            const float v0 = fs[2 * p], v1 = fs[2 * p + 1];
            g += v0 * v0 + v1 * v1;
            hw[p] = packhh((__bf16)(v0 * SCALE), (__bf16)(v1 * SCALE));
        }
        const float gp = 0.5f * LOG2E * g;   // log2-domain column/row norm
        unsigned int* __restrict__ H = half ? BH : AH;
        const int o = off(r);
        *(uint4*)&H[o]     = make_uint4(hw[0], hw[1], hw[2], hw[3]);
        *(uint4*)&H[o + 4] = make_uint4(hw[4], hw[5], hw[6], hw[7]);
        if (half) {
            // -g as hi+lo bf16 (residual ~6e-5 in the exponent)
            const __bf16 nh = (__bf16)(-gp);
            const __bf16 nl = (__bf16)(-(gp + (float)nh));
            *(uint4*)&BG[r * 4] = make_uint4(packhh(nh, nl), 0u, 0u, 0u);
        } else {
            srg[r] = gp;
        }
    }
    __syncthreads();

    // ---- A fragments: quads 0/1 = data (k0..15); quad 2 = {1,1,0..}
    //      (k16,k17 multiply B's -g channels); quad 3 = zeros ----
    bf16x8 a1f[2];
    {
#pragma unroll
        for (int rt = 0; rt < 2; ++rt) {
            FragU u;
            if (quad < 2) {
                const int row = w * 32 + rt * 16 + l15;
                u.q = *(const uint4*)&AH[off(row) + qh * 4];
            } else {
                u.q = make_uint4((quad == 2) ? ONEONE : 0u, 0u, 0u, 0u);
            }
            a1f[rt] = u.v;
        }
    }

    // per-lane B-fragment base pointer + per-jt stride (dwords)
    const unsigned int* bptr;
    int bstride;
    if (quad < 2)      { bptr = &BH[off(l15) + qh * 4]; bstride = 144; }
    else if (quad == 2){ bptr = &BG[l15 * 4];           bstride = 64;  }
    else               { bptr = &zero4[0];              bstride = 0;   }

    float sum[2][4] = {{0.f, 0.f, 0.f, 0.f}, {0.f, 0.f, 0.f, 0.f}};

    // ---- software-pipelined main loop: MFMA tile jt, exp tile jt-1 ----
    floatx4 accP[2], accC[2];
    {
        FragU b; b.q = *(const uint4*)bptr; bptr += bstride;
        floatx4 zc = {0.f, 0.f, 0.f, 0.f};
        accP[0] = __builtin_amdgcn_mfma_f32_16x16x32_bf16(a1f[0], b.v, zc, 0, 0, 0);
        accP[1] = __builtin_amdgcn_mfma_f32_16x16x32_bf16(a1f[1], b.v, zc, 0, 0, 0);
    }
#pragma unroll
    for (int jt = 1; jt < 8; ++jt) {
        FragU b; b.q = *(const uint4*)bptr; bptr += bstride;
        floatx4 zc = {0.f, 0.f, 0.f, 0.f};
        accC[0] = __builtin_amdgcn_mfma_f32_16x16x32_bf16(a1f[0], b.v, zc, 0, 0, 0);
        accC[1] = __builtin_amdgcn_mfma_f32_16x16x32_bf16(a1f[1], b.v, zc, 0, 0, 0);
#pragma unroll
        for (int rt = 0; rt < 2; ++rt)
#pragma unroll
            for (int r = 0; r < 4; ++r)
                sum[rt][r] += __builtin_amdgcn_exp2f(accP[rt][r]);
        accP[0] = accC[0];
        accP[1] = accC[1];
    }
#pragma unroll
    for (int rt = 0; rt < 2; ++rt)
#pragma unroll
        for (int r = 0; r < 4; ++r)
            sum[rt][r] += __builtin_amdgcn_exp2f(accP[rt][r]);

    // ---- epilogue: row-scale by 2^-g_row, wave reduce, per-wave store ----
    float tot = 0.f;
#pragma unroll
    for (int rt = 0; rt < 2; ++rt)
#pragma unroll
        for (int r = 0; r < 4; ++r) {
            const float rs = __builtin_amdgcn_exp2f(-srg[w * 32 + rt * 16 + quad * 4 + r]);
            tot = fmaf(sum[rt][r], rs, tot);
        }
    for (int o = 32; o > 0; o >>= 1) tot += __shfl_down(tot, o, 64);

    if (lane == 0) {
        float wt = (t == 0 || t == 127) ? 1.f : 2.f;
        if (isxx && sq > sa) wt *= 2.f;   // symmetric off-diag strip-pair
        const int idx = isxx ? (2048 + t * 10 + (slot - 16)) : (t * 16 + slot);
        part[idx * 4 + w] = wt * tot;     // per-wave partial, no block reduce
    }

    // ---- fused finalize: last-block ticket (device-scope, G16) ----
    __syncthreads();                      // all 4 part-stores issued & complete
    if (tid == 0) {
        __threadfence();                  // release: writeback local L2
        lastflag = (atomicAdd(cnt, 1u) == (unsigned)(NBLK - 1));
    }
    __syncthreads();
    if (!lastflag) return;

    __threadfence();                      // acquire: invalidate stale caches
    double vxy = 0.0, vxx = 0.0;
#pragma unroll
    for (int k = 0; k < 32; ++k)  vxy += (double)part[tid + 256 * k];   // [0,8192)
#pragma unroll
    for (int k = 32; k < 52; ++k) vxx += (double)part[tid + 256 * k];   // [8192,13312)
    for (int o = 32; o > 0; o >>= 1) {
        vxx += __shfl_down(vxx, o, 64);
        vxy += __shfl_down(vxy, o, 64);
    }
    if (lane == 0) { dred[w] = vxx; dred[4 + w] = vxy; }
    __syncthreads();
    if (tid == 0) {
        double sxx = dred[0] + dred[1] + dred[2] + dred[3];
        double sxy = dred[4] + dred[5] + dred[6] + dred[7];
        // diagonal entries (~1.0 each) included in sxx: subtract 254*512
        double e1 = (sxx - 254.0 * 512.0) / (254.0 * 512.0 * 511.0);
        double e2 = sxy / (254.0 * 512.0 * 512.0);
        out[0] = (float)(e1 - 2.0 * e2);
    }
}

extern "C" void kernel_launch(void* const* d_in, const int* in_sizes, int n_in,
                              void* d_out, int out_size, void* d_ws, size_t ws_size,
                              hipStream_t stream) {
    (void)in_sizes; (void)n_in; (void)out_size; (void)ws_size;
    const float* x = (const float*)d_in[0];
    const float* y = (const float*)d_in[1];
    float* out  = (float*)d_out;
    float* part = (float*)d_ws;   // 13312 floats: [0,8192) xy, [8192,13312) xx
    unsigned int* cnt = (unsigned int*)((char*)d_ws + 13312 * sizeof(float));

    // ws is re-poisoned by the harness each iteration: zero the ticket in-stream.
    hipMemsetAsync(cnt, 0, sizeof(unsigned int), stream);
    mmd_kernel<<<dim3(NSLOT, 128), dim3(256), 0, stream>>>(x, y, part, cnt, out);
}

// Round 5
// 71.168 us; speedup vs baseline: 2.3267x; 2.3267x over previous
//
#include <hip/hip_runtime.h>

// RBF-MMD discriminator: B=512 rows, T=128 slabs, C=16, fp32.
// out = E_xx - 2*E_xy over per-slab RBF grams (slab weight 1 for t in {0,127},
// else 2; 254 weighted slab instances).
//
// R13 = exact revert to R8 (best measured, 70.9us). Session evidence ledger:
//  R9  (4-slab batching, lb(256,4)):      +6us  — residency/quantization loss
//  R10 (drop cross-wave reduce+barrier):  +0.4  — barrier not on critical path
//  R11 (coalesced 4-lane/row staging):    +1.4  — TA line-divergence theory dead
//  R12 (fused finalize, ticket+fences):   +95   — per-block device-scope release
//       fence + same-address atomic serializes ~27ns/block across 3328 blocks;
//       cross-XCD visibility makes the ticket pattern expensive (G12/G16).
// Component budget from R12's counters: fill 41.5us @82% HBM (harness-owned) +
// resets/gaps ~8us + mmd ~16-18us (VALU-busy floor ~8.5us: exp2 + bf16 staging
// conversions; MFMA 1.3us; mem 2us) + finalize+gap ~4us. The ~8us of mmd
// latency slack resisted four structural attacks; further rounds are negative-EV.
//
// Kernel structure (R8): grid (26,128), 1 t-slab/block, 4 waves, 11.9KB LDS,
// ~8 blocks/CU. Per-entry math: pure-bf16 dot (SCALE=sqrt(log2e) folded into
// operands), -|col|^2/2 in log2 domain folded into MFMA K-slots 16/17 via
// hi+lo bf16 channels against A={1,1}; acc = log2e*(dot - |col|^2/2), so
// per-entry work = exp2 + add. Row-scale 2^-g_row epilogue.
// Kxx symmetry: strip-pairs q>=a only, q>a weighted 2x (exact).

#define LOG2E 1.4426950408889634f
#define SCALE 1.2011224087864498f   // sqrt(LOG2E)

typedef __attribute__((ext_vector_type(8))) __bf16 bf16x8;
typedef __attribute__((ext_vector_type(4))) float floatx4;

union FragU { uint4 q; unsigned int u[4]; bf16x8 v; };

// 16B-aligned group-padded LDS row offset (dwords): 8 dw/row + 4 dw pad per 4 rows.
static __device__ __forceinline__ int off(int n) { return (n << 3) + ((n >> 2) << 2); }

static __device__ __forceinline__ unsigned short bfbits(__bf16 h) {
    union { __bf16 h; unsigned short s; } u; u.h = h; return u.s;
}
static __device__ __forceinline__ unsigned int packhh(__bf16 a, __bf16 b) {
    return (unsigned int)bfbits(a) | ((unsigned int)bfbits(b) << 16);
}

#define NSLOT 26
#define ONEONE 0x3F803F80u   // packed bf16 {1.0, 1.0}

// grid (26,128): blockIdx.x = pair slot, blockIdx.y = t.
// slot<16: xy block, a=slot>>2 (A strip of X), q=slot&3 (col strip of Y).
// slot>=16: xx block over triangular (a,q), q>=a, weight 2 if q>a.
// 4 waves; wave w owns A rows a*128 + w*32 (two 16-row tiles).
__global__ __launch_bounds__(256, 8) void mmd_kernel(const float* __restrict__ x,
                                                     const float* __restrict__ y,
                                                     float* __restrict__ part) {
    __shared__ unsigned int AH[1152], BH[1152];
    __shared__ unsigned int BG[512];      // per B-row: {pack(-ghi,-glo),0,0,0}
    __shared__ float srg[128];            // g per A-row
    __shared__ unsigned int zero4[4];
    __shared__ float red[4];

    const int slot = blockIdx.x;
    const int t    = blockIdx.y;
    const int tid  = threadIdx.x;
    const int w    = tid >> 6;
    const int lane = tid & 63;
    const int quad = lane >> 4;
    const int l15  = lane & 15;
    const int qh   = quad & 1;

    int sa, sq, isxx;
    if (slot < 16) { isxx = 0; sa = slot >> 2; sq = slot & 3; }
    else {
        isxx = 1;
        const int s = slot - 16;
        if      (s < 4) { sa = 0; sq = s; }
        else if (s < 7) { sa = 1; sq = s - 3; }
        else if (s < 9) { sa = 2; sq = s - 5; }
        else            { sa = 3; sq = 3; }
    }

    if (tid == 0) { zero4[0] = 0u; zero4[1] = 0u; zero4[2] = 0u; zero4[3] = 0u; }

    // ---- staging: threads 0..127 convert A-rows (X), 128..255 B-rows ----
    {
        const int half = tid >> 7;
        const int r    = tid & 127;
        const int grow = (half ? sq : sa) * 128 + r;
        const float4* __restrict__ src4 =
            (half && !isxx) ? (const float4*)y : (const float4*)x;
        const size_t gb = (size_t)grow * 512 + t * 4;
        float4 f0 = src4[gb], f1 = src4[gb + 1], f2 = src4[gb + 2], f3 = src4[gb + 3];
        const float fs[16] = { f0.x, f0.y, f0.z, f0.w, f1.x, f1.y, f1.z, f1.w,
                               f2.x, f2.y, f2.z, f2.w, f3.x, f3.y, f3.z, f3.w };
        float g = 0.f;
        unsigned int hw[8];
#pragma unroll
        for (int p = 0; p < 8; ++p) {
            const float v0 = fs[2 * p], v1 = fs[2 * p + 1];
            g += v0 * v0 + v1 * v1;
            hw[p] = packhh((__bf16)(v0 * SCALE), (__bf16)(v1 * SCALE));
        }
        const float gp = 0.5f * LOG2E * g;   // log2-domain column/row norm
        unsigned int* __restrict__ H = half ? BH : AH;
        const int o = off(r);
        *(uint4*)&H[o]     = make_uint4(hw[0], hw[1], hw[2], hw[3]);
        *(uint4*)&H[o + 4] = make_uint4(hw[4], hw[5], hw[6], hw[7]);
        if (half) {
            // -g as hi+lo bf16 (residual ~6e-5 in the exponent)
            const __bf16 nh = (__bf16)(-gp);
            const __bf16 nl = (__bf16)(-(gp + (float)nh));
            *(uint4*)&BG[r * 4] = make_uint4(packhh(nh, nl), 0u, 0u, 0u);
        } else {
            srg[r] = gp;
        }
    }
    __syncthreads();

    // ---- A fragments: quads 0/1 = hi data (k0..15); quad 2 = {1,1,0..}
    //      (k16,k17 multiply B's -g channels); quad 3 = zeros ----
    bf16x8 a1f[2];
    {
#pragma unroll
        for (int rt = 0; rt < 2; ++rt) {
            FragU u;
            if (quad < 2) {
                const int row = w * 32 + rt * 16 + l15;
                u.q = *(const uint4*)&AH[off(row) + qh * 4];
            } else {
                u.q = make_uint4((quad == 2) ? ONEONE : 0u, 0u, 0u, 0u);
            }
            a1f[rt] = u.v;
        }
    }

    // per-lane B-fragment base pointer + per-jt stride (dwords)
    const unsigned int* bptr;
    int bstride;
    if (quad < 2)      { bptr = &BH[off(l15) + qh * 4]; bstride = 144; }
    else if (quad == 2){ bptr = &BG[l15 * 4];           bstride = 64;  }
    else               { bptr = &zero4[0];              bstride = 0;   }

    float sum[2][4] = {{0.f, 0.f, 0.f, 0.f}, {0.f, 0.f, 0.f, 0.f}};

    // ---- software-pipelined main loop: MFMA tile jt, exp tile jt-1 ----
    floatx4 accP[2], accC[2];
    {
        FragU b; b.q = *(const uint4*)bptr; bptr += bstride;
        floatx4 zc = {0.f, 0.f, 0.f, 0.f};
        accP[0] = __builtin_amdgcn_mfma_f32_16x16x32_bf16(a1f[0], b.v, zc, 0, 0, 0);
        accP[1] = __builtin_amdgcn_mfma_f32_16x16x32_bf16(a1f[1], b.v, zc, 0, 0, 0);
    }
#pragma unroll
    for (int jt = 1; jt < 8; ++jt) {
        FragU b; b.q = *(const uint4*)bptr; bptr += bstride;
        floatx4 zc = {0.f, 0.f, 0.f, 0.f};
        accC[0] = __builtin_amdgcn_mfma_f32_16x16x32_bf16(a1f[0], b.v, zc, 0, 0, 0);
        accC[1] = __builtin_amdgcn_mfma_f32_16x16x32_bf16(a1f[1], b.v, zc, 0, 0, 0);
#pragma unroll
        for (int rt = 0; rt < 2; ++rt)
#pragma unroll
            for (int r = 0; r < 4; ++r)
                sum[rt][r] += __builtin_amdgcn_exp2f(accP[rt][r]);
        accP[0] = accC[0];
        accP[1] = accC[1];
    }
#pragma unroll
    for (int rt = 0; rt < 2; ++rt)
#pragma unroll
        for (int r = 0; r < 4; ++r)
            sum[rt][r] += __builtin_amdgcn_exp2f(accP[rt][r]);

    // ---- epilogue: row-scale by 2^-g_row, block reduce, store to slot ----
    float tot = 0.f;
#pragma unroll
    for (int rt = 0; rt < 2; ++rt)
#pragma unroll
        for (int r = 0; r < 4; ++r) {
            const float rs = __builtin_amdgcn_exp2f(-srg[w * 32 + rt * 16 + quad * 4 + r]);
            tot = fmaf(sum[rt][r], rs, tot);
        }
    for (int o = 32; o > 0; o >>= 1) tot += __shfl_down(tot, o, 64);
    if (lane == 0) red[w] = tot;
    __syncthreads();
    if (tid == 0) {
        float wt = (t == 0 || t == 127) ? 1.f : 2.f;
        if (isxx && sq > sa) wt *= 2.f;   // symmetric off-diag strip-pair
        const int idx = isxx ? (2048 + t * 10 + (slot - 16)) : (t * 16 + slot);
        part[idx] = wt * (red[0] + red[1] + red[2] + red[3]);
    }
}

__global__ __launch_bounds__(256) void finalize_kernel(const float* __restrict__ part,
                                                       float* __restrict__ out) {
    const int tid = threadIdx.x;
    double vxy = 0.0, vxx = 0.0;
#pragma unroll
    for (int k = 0; k < 8; ++k)  vxy += (double)part[tid + 256 * k];      // [0,2048)
#pragma unroll
    for (int k = 8; k < 13; ++k) vxx += (double)part[tid + 256 * k];      // [2048,3328)
    for (int o = 32; o > 0; o >>= 1) {
        vxx += __shfl_down(vxx, o, 64);
        vxy += __shfl_down(vxy, o, 64);
    }
    __shared__ double red[8];
    const int wid = tid >> 6;
    if ((tid & 63) == 0) { red[wid] = vxx; red[4 + wid] = vxy; }
    __syncthreads();
    if (tid == 0) {
        double sxx = red[0] + red[1] + red[2] + red[3];
        double sxy = red[4] + red[5] + red[6] + red[7];
        // diagonal entries (~1.0 each) included in sxx: subtract 254*512
        double e1 = (sxx - 254.0 * 512.0) / (254.0 * 512.0 * 511.0);
        double e2 = sxy / (254.0 * 512.0 * 512.0);
        out[0] = (float)(e1 - 2.0 * e2);
    }
}

extern "C" void kernel_launch(void* const* d_in, const int* in_sizes, int n_in,
                              void* d_out, int out_size, void* d_ws, size_t ws_size,
                              hipStream_t stream) {
    (void)in_sizes; (void)n_in; (void)out_size; (void)ws_size;
    const float* x = (const float*)d_in[0];
    const float* y = (const float*)d_in[1];
    float* out  = (float*)d_out;
    float* part = (float*)d_ws;   // 3328 floats: [0,2048) xy, [2048,3328) xx

    mmd_kernel<<<dim3(NSLOT, 128), dim3(256), 0, stream>>>(x, y, part);
    finalize_kernel<<<dim3(1), dim3(256), 0, stream>>>(part, out);
}